// Round 6
// baseline (228.885 us; speedup 1.0000x reference)
//
#include <hip/hip_runtime.h>

#define B_  2
#define S_  2048
#define D_  1024
#define H_  16
#define HD_ 64
#define M_  4096   // B_*S_

typedef __attribute__((ext_vector_type(8))) short  short8;
typedef __attribute__((ext_vector_type(4))) float  floatx4;

__device__ __forceinline__ unsigned short f2bf(float f) {
  unsigned int u = __float_as_uint(f);
  u = (u + 0x7fffu + ((u >> 16) & 1u)) >> 16;   // RNE
  return (unsigned short)u;
}

// async global->LDS, 16B per lane; lds dest = wave-uniform base + lane*16
__device__ __forceinline__ void gl_lds16(const short* g, short* l) {
  __builtin_amdgcn_global_load_lds(
      (const __attribute__((address_space(1))) unsigned int*)g,
      (__attribute__((address_space(3))) unsigned int*)l, 16, 0, 0);
}

// ---------------------------------------------------------------- cast fp32->bf16
__global__ __launch_bounds__(256) void cast_kernel(
    const float* __restrict__ x,  const float* __restrict__ wq,
    const float* __restrict__ wk, const float* __restrict__ wv,
    const float* __restrict__ wo,
    short* __restrict__ xb,  short* __restrict__ wqb, short* __restrict__ wkb,
    short* __restrict__ wvb, short* __restrict__ wob) {
  const float* src; short* dst; int n8;
  switch (blockIdx.y) {
    case 0:  src = x;  dst = xb;  n8 = (M_ * D_) / 8; break;
    case 1:  src = wq; dst = wqb; n8 = (D_ * D_) / 8; break;
    case 2:  src = wk; dst = wkb; n8 = (D_ * D_) / 8; break;
    case 3:  src = wv; dst = wvb; n8 = (D_ * D_) / 8; break;
    default: src = wo; dst = wob; n8 = (D_ * D_) / 8; break;
  }
  int i = blockIdx.x * 256 + threadIdx.x;
  if (i >= n8) return;
  float4 a = ((const float4*)src)[2 * i];
  float4 b = ((const float4*)src)[2 * i + 1];
  short8 o;
  o[0] = (short)f2bf(a.x); o[1] = (short)f2bf(a.y);
  o[2] = (short)f2bf(a.z); o[3] = (short)f2bf(a.w);
  o[4] = (short)f2bf(b.x); o[5] = (short)f2bf(b.y);
  o[6] = (short)f2bf(b.z); o[7] = (short)f2bf(b.w);
  ((short8*)dst)[i] = o;
}

// ---------------------------------------------------------------- QKV projection
// m97 structure, BK=64: global_load_lds w=16, unpadded As/Bs [128][64], 16 K-iters.
// C[m][n] = sum_k A[m][k]*W[n][k]; writes [B,H,S,HD] bf16; Q scaled 0.125*log2e.
__global__ __launch_bounds__(256) void gemm_qkv(
    const short* __restrict__ xb,  const short* __restrict__ wqb,
    const short* __restrict__ wkb, const short* __restrict__ wvb,
    short* __restrict__ qo, short* __restrict__ ko, short* __restrict__ vo) {
  __shared__ alignas(16) short As[128 * 64];   // 128B/row
  __shared__ alignas(16) short Bs[128 * 64];
  const int tid  = threadIdx.x;
  const int lane = tid & 63, wid = tid >> 6;
  const int quad = lane >> 4, l16 = lane & 15;
  const int bn = blockIdx.x, bm = blockIdx.y, z = blockIdx.z;
  const short* wsel = (z == 0) ? wqb : ((z == 1) ? wkb : wvb);
  short*       osel = (z == 0) ? qo  : ((z == 1) ? ko  : vo);
  const float scale = (z == 0) ? 0.125f * 1.44269504f : 1.0f;
  // staging: wave w fills rows w*32..+31; one instr = 64 lanes x 16B = 8 rows
  const int srow = wid * 32 + (lane >> 3);
  const int scol = (lane & 7) * 8;             // shorts
  const short* ag = xb   + (bm * 128 + srow) * D_ + scol;
  const short* bg = wsel + (bn * 128 + srow) * D_ + scol;
  const int wm = (wid & 1) * 64, wn = (wid >> 1) * 64;
  floatx4 acc[4][4];
#pragma unroll
  for (int i = 0; i < 4; i++)
#pragma unroll
    for (int j = 0; j < 4; j++) acc[i][j] = (floatx4){0.f, 0.f, 0.f, 0.f};

  for (int k0 = 0; k0 < D_; k0 += 64) {
    __syncthreads();
#pragma unroll
    for (int i = 0; i < 4; i++) {
      gl_lds16(ag + i * 8 * D_ + k0, &As[(wid * 32 + i * 8) * 64]);
      gl_lds16(bg + i * 8 * D_ + k0, &Bs[(wid * 32 + i * 8) * 64]);
    }
    __syncthreads();                 // vmcnt(0) drain -> LDS ready
    short8 af[4][2], bf[4][2];
#pragma unroll
    for (int t = 0; t < 4; t++)
#pragma unroll
      for (int kk = 0; kk < 2; kk++) {
        af[t][kk] = *(const short8*)&As[(wm + t * 16 + l16) * 64 + kk * 32 + quad * 8];
        bf[t][kk] = *(const short8*)&Bs[(wn + t * 16 + l16) * 64 + kk * 32 + quad * 8];
      }
#pragma unroll
    for (int kk = 0; kk < 2; kk++)
#pragma unroll
      for (int tm = 0; tm < 4; tm++)
#pragma unroll
        for (int tn = 0; tn < 4; tn++)
          acc[tm][tn] = __builtin_amdgcn_mfma_f32_16x16x32_bf16(af[tm][kk], bf[tn][kk], acc[tm][tn], 0, 0, 0);
  }
#pragma unroll
  for (int tm = 0; tm < 4; tm++) {
#pragma unroll
    for (int tn = 0; tn < 4; tn++) {
      int n = bn * 128 + wn + tn * 16 + l16;
      int h = n >> 6, hd = n & 63;
#pragma unroll
      for (int r = 0; r < 4; r++) {
        int m = bm * 128 + wm + tm * 16 + quad * 4 + r;
        int b = m >> 11, s = m & 2047;
        osel[((b * H_ + h) * S_ + s) * HD_ + hd] = (short)f2bf(acc[tm][tn][r] * scale);
      }
    }
  }
}

// ---------------------------------------------------------------- V transpose
// V [BH][S][HD] -> Vt [BH][HD][S], 64x64 LDS tiles
__global__ __launch_bounds__(256) void transpose_v(
    const short* __restrict__ v, short* __restrict__ vt) {
  __shared__ alignas(16) short t[64][72];
  const int tid = threadIdx.x;
  const int s0 = blockIdx.x * 64;
  const int base = blockIdx.y * (S_ * HD_);
  const int row = tid >> 2, c8 = (tid & 3) * 16;
  short8 a0 = *(const short8*)(v + base + (s0 + row) * HD_ + c8);
  short8 a1 = *(const short8*)(v + base + (s0 + row) * HD_ + c8 + 8);
  *(short8*)&t[row][c8]     = a0;
  *(short8*)&t[row][c8 + 8] = a1;
  __syncthreads();
  short8 o0, o1;
#pragma unroll
  for (int j = 0; j < 8; j++) {
    o0[j] = t[c8 + j][row];
    o1[j] = t[c8 + 8 + j][row];
  }
  *(short8*)(vt + base + row * S_ + s0 + c8)     = o0;
  *(short8*)(vt + base + row * S_ + s0 + c8 + 8) = o1;
}

// ---------------------------------------------------------------- output projection
__global__ __launch_bounds__(256) void gemm_out(
    const short* __restrict__ cx, const short* __restrict__ wob,
    const float* __restrict__ bo, float* __restrict__ out) {
  __shared__ alignas(16) short As[128 * 64];
  __shared__ alignas(16) short Bs[128 * 64];
  const int tid  = threadIdx.x;
  const int lane = tid & 63, wid = tid >> 6;
  const int quad = lane >> 4, l16 = lane & 15;
  const int bn = blockIdx.x, bm = blockIdx.y;
  const int srow = wid * 32 + (lane >> 3);
  const int scol = (lane & 7) * 8;
  const short* ag = cx  + (bm * 128 + srow) * D_ + scol;
  const short* bg = wob + (bn * 128 + srow) * D_ + scol;
  const int wm = (wid & 1) * 64, wn = (wid >> 1) * 64;
  floatx4 acc[4][4];
#pragma unroll
  for (int i = 0; i < 4; i++)
#pragma unroll
    for (int j = 0; j < 4; j++) acc[i][j] = (floatx4){0.f, 0.f, 0.f, 0.f};

  for (int k0 = 0; k0 < D_; k0 += 64) {
    __syncthreads();
#pragma unroll
    for (int i = 0; i < 4; i++) {
      gl_lds16(ag + i * 8 * D_ + k0, &As[(wid * 32 + i * 8) * 64]);
      gl_lds16(bg + i * 8 * D_ + k0, &Bs[(wid * 32 + i * 8) * 64]);
    }
    __syncthreads();
    short8 af[4][2], bf[4][2];
#pragma unroll
    for (int t = 0; t < 4; t++)
#pragma unroll
      for (int kk = 0; kk < 2; kk++) {
        af[t][kk] = *(const short8*)&As[(wm + t * 16 + l16) * 64 + kk * 32 + quad * 8];
        bf[t][kk] = *(const short8*)&Bs[(wn + t * 16 + l16) * 64 + kk * 32 + quad * 8];
      }
#pragma unroll
    for (int kk = 0; kk < 2; kk++)
#pragma unroll
      for (int tm = 0; tm < 4; tm++)
#pragma unroll
        for (int tn = 0; tn < 4; tn++)
          acc[tm][tn] = __builtin_amdgcn_mfma_f32_16x16x32_bf16(af[tm][kk], bf[tn][kk], acc[tm][tn], 0, 0, 0);
  }
#pragma unroll
  for (int tn = 0; tn < 4; tn++) {
    int n = bn * 128 + wn + tn * 16 + l16;
    float bias = bo[n];
#pragma unroll
    for (int tm = 0; tm < 4; tm++) {
#pragma unroll
      for (int r = 0; r < 4; r++) {
        int m = bm * 128 + wm + tm * 16 + quad * 4 + r;
        out[m * D_ + n] = acc[tm][tn][r] + bias;
      }
    }
  }
}

// ---------------------------------------------------------------- flash attention
// 32 Q-rows per wave (two 16-row m-sets share K/V frags + barriers), 128 Q-rows
// per block. Single-buffered K/V, 2 barriers/iter (R3 structure). Fixed-rebase
// softmax p = 2^(y-32), y = score*log2e folded into Q scale; 2^-32 cancels in o/l.
// grid (S/128, B*H); LPT qblk = 15 - bx.
__global__ __launch_bounds__(256) void attn_kernel(
    const short* __restrict__ qbuf, const short* __restrict__ kbuf,
    const short* __restrict__ vtbuf, short* __restrict__ ctx) {
  __shared__ alignas(16) short Ks[64][72];      // [s][hd]
  __shared__ alignas(16) short Vs[64][72];      // [hd][s]
  __shared__ alignas(16) short Ps[4][32][72];   // per-wave P, 32 rows
  const int tid  = threadIdx.x;
  const int lane = tid & 63, wid = tid >> 6;
  const int quad = lane >> 4, l16 = lane & 15;
  const int qblk = 15 - blockIdx.x, bh = blockIdx.y;   // LPT: longest first
  const int base = bh * (S_ * HD_);
  const int q0 = qblk * 128 + wid * 32;   // first of this wave's 32 rows

  short8 qf[2][2];
#pragma unroll
  for (int ms = 0; ms < 2; ms++) {
    qf[ms][0] = *(const short8*)(qbuf + base + (q0 + ms * 16 + l16) * HD_ + quad * 8);
    qf[ms][1] = *(const short8*)(qbuf + base + (q0 + ms * 16 + l16) * HD_ + 32 + quad * 8);
  }

  float lsum[2][4];
  floatx4 o[2][4];
#pragma unroll
  for (int ms = 0; ms < 2; ms++)
#pragma unroll
    for (int r = 0; r < 4; r++) { lsum[ms][r] = 0.f; o[ms][r] = (floatx4){0.f, 0.f, 0.f, 0.f}; }

  const int row = tid >> 2, c8 = (tid & 3) * 16;   // staging coords
  const short* kg = kbuf  + base + row * HD_ + c8;
  const short* vg = vtbuf + base + row * S_  + c8;  // row = hd
  short8 kv0 = *(const short8*)(kg);
  short8 kv1 = *(const short8*)(kg + 8);
  short8 vv0 = *(const short8*)(vg);
  short8 vv1 = *(const short8*)(vg + 8);

  const int nkt = 2 * (qblk + 1);
  for (int kt = 0; kt < nkt; kt++) {
    __syncthreads();
    *(short8*)&Ks[row][c8]     = kv0;
    *(short8*)&Ks[row][c8 + 8] = kv1;
    *(short8*)&Vs[row][c8]     = vv0;
    *(short8*)&Vs[row][c8 + 8] = vv1;
    __syncthreads();
    {   // prefetch next tile (clamped; last-iter value unused)
      const int ktn = (kt + 1 < nkt) ? kt + 1 : kt;
      const short* kgn = kg + ktn * 64 * HD_;
      const short* vgn = vg + ktn * 64;
      kv0 = *(const short8*)(kgn);
      kv1 = *(const short8*)(kgn + 8);
      vv0 = *(const short8*)(vgn);
      vv1 = *(const short8*)(vgn + 8);
    }
    if (kt * 64 <= q0 + 31) {     // wave has at least one unmasked row
      // QK: sc[ms][ct], K frags shared across the two m-sets
      floatx4 sc[2][4];
#pragma unroll
      for (int ct = 0; ct < 4; ct++) {
        short8 kb0 = *(const short8*)&Ks[ct * 16 + l16][quad * 8];
        short8 kb1 = *(const short8*)&Ks[ct * 16 + l16][32 + quad * 8];
#pragma unroll
        for (int ms = 0; ms < 2; ms++) {
          floatx4 zz = (floatx4){0.f, 0.f, 0.f, 0.f};
          zz          = __builtin_amdgcn_mfma_f32_16x16x32_bf16(qf[ms][0], kb0, zz, 0, 0, 0);
          sc[ms][ct]  = __builtin_amdgcn_mfma_f32_16x16x32_bf16(qf[ms][1], kb1, zz, 0, 0, 0);
        }
      }
      // causal mask (only boundary tiles need it; wave-uniform branch)
#pragma unroll
      for (int ms = 0; ms < 2; ms++) {
        if (kt * 64 + 63 > q0 + ms * 16) {
#pragma unroll
          for (int ct = 0; ct < 4; ct++)
#pragma unroll
            for (int r = 0; r < 4; r++)
              if (kt * 64 + ct * 16 + l16 > q0 + ms * 16 + quad * 4 + r)
                sc[ms][ct][r] = -INFINITY;
        }
      }
      // softmax (no max-tracking) + P to LDS (truncating bf16: p >= 0)
#pragma unroll
      for (int ms = 0; ms < 2; ms++)
#pragma unroll
        for (int r = 0; r < 4; r++)
#pragma unroll
          for (int ct = 0; ct < 4; ct++) {
            float p = __builtin_amdgcn_exp2f(sc[ms][ct][r] - 32.0f);
            lsum[ms][r] += p;
            Ps[wid][ms * 16 + quad * 4 + r][ct * 16 + l16] = (short)(__float_as_uint(p) >> 16);
          }
      // PV: o[ms] += P[ms] * V ; V frags shared across m-sets
#pragma unroll
      for (int ks = 0; ks < 2; ks++) {
        short8 vb[4];
#pragma unroll
        for (int nt = 0; nt < 4; nt++)
          vb[nt] = *(const short8*)&Vs[nt * 16 + l16][ks * 32 + quad * 8];
#pragma unroll
        for (int ms = 0; ms < 2; ms++) {
          short8 pa = *(const short8*)&Ps[wid][ms * 16 + l16][ks * 32 + quad * 8];
#pragma unroll
          for (int nt = 0; nt < 4; nt++)
            o[ms][nt] = __builtin_amdgcn_mfma_f32_16x16x32_bf16(pa, vb[nt], o[ms][nt], 0, 0, 0);
        }
      }
    }
  }
  // epilogue: cross-lane l reduction (within 16-lane groups), then write ctx
#pragma unroll
  for (int ms = 0; ms < 2; ms++)
#pragma unroll
    for (int r = 0; r < 4; r++) {
      float ls = lsum[ms][r];
      ls += __shfl_xor(ls, 1);
      ls += __shfl_xor(ls, 2);
      ls += __shfl_xor(ls, 4);
      ls += __shfl_xor(ls, 8);
      float linv = 1.f / ls;
      int s = q0 + ms * 16 + quad * 4 + r;
      int rowbase = ((bh >> 4) * S_ + s) * D_ + (bh & 15) * HD_;
#pragma unroll
      for (int nt = 0; nt < 4; nt++)
        ctx[rowbase + nt * 16 + l16] = (short)f2bf(o[ms][nt][r] * linv);
    }
}

// ---------------------------------------------------------------- launch
extern "C" void kernel_launch(void* const* d_in, const int* in_sizes, int n_in,
                              void* d_out, int out_size, void* d_ws, size_t ws_size,
                              hipStream_t stream) {
  const float* x  = (const float*)d_in[0];
  const float* wq = (const float*)d_in[1];
  const float* wk = (const float*)d_in[2];
  const float* wv = (const float*)d_in[3];
  const float* wo = (const float*)d_in[4];
  const float* bo = (const float*)d_in[5];
  float* out = (float*)d_out;

  char* ws = (char*)d_ws;
  short* xb  = (short*)(ws);                    // 8 MB
  short* wqb = (short*)(ws + (8u  << 20));      // 2 MB
  short* wkb = (short*)(ws + (10u << 20));      // 2 MB
  short* wvb = (short*)(ws + (12u << 20));      // 2 MB
  short* wob = (short*)(ws + (14u << 20));      // 2 MB
  short* qb  = (short*)(ws + (16u << 20));      // 8 MB  [B,H,S,HD]
  short* kb  = (short*)(ws + (24u << 20));      // 8 MB
  short* vb  = (short*)(ws + (32u << 20));      // 8 MB
  short* cx  = (short*)(ws + (40u << 20));      // 8 MB  [M,D]
  short* vtb = (short*)(ws + (48u << 20));      // 8 MB  [B,H,HD,S] -> total 56 MB

  cast_kernel<<<dim3(2048, 5), 256, 0, stream>>>(x, wq, wk, wv, wo, xb, wqb, wkb, wvb, wob);
  gemm_qkv   <<<dim3(8, 32, 3), 256, 0, stream>>>(xb, wqb, wkb, wvb, qb, kb, vb);
  transpose_v<<<dim3(32, 32),   256, 0, stream>>>(vb, vtb);
  attn_kernel<<<dim3(16, 32),   256, 0, stream>>>(qb, kb, vtb, cx);
  gemm_out   <<<dim3(8, 32),    256, 0, stream>>>(cx, wob, bo, out);
}

// Round 7
// 208.740 us; speedup vs baseline: 1.0965x; 1.0965x over previous
//
#include <hip/hip_runtime.h>

#define B_  2
#define S_  2048
#define D_  1024
#define H_  16
#define HD_ 64
#define M_  4096   // B_*S_

typedef __attribute__((ext_vector_type(8))) short  short8;
typedef __attribute__((ext_vector_type(4))) float  floatx4;

__device__ __forceinline__ unsigned short f2bf(float f) {
  unsigned int u = __float_as_uint(f);
  u = (u + 0x7fffu + ((u >> 16) & 1u)) >> 16;   // RNE
  return (unsigned short)u;
}

// async global->LDS, 16B per lane; lds dest = wave-uniform base + lane*16
__device__ __forceinline__ void gl_lds16(const short* g, short* l) {
  __builtin_amdgcn_global_load_lds(
      (const __attribute__((address_space(1))) unsigned int*)g,
      (__attribute__((address_space(3))) unsigned int*)l, 16, 0, 0);
}

// ---------------------------------------------------------------- cast fp32->bf16
__global__ __launch_bounds__(256) void cast_kernel(
    const float* __restrict__ x,  const float* __restrict__ wq,
    const float* __restrict__ wk, const float* __restrict__ wv,
    const float* __restrict__ wo,
    short* __restrict__ xb,  short* __restrict__ wqb, short* __restrict__ wkb,
    short* __restrict__ wvb, short* __restrict__ wob) {
  const float* src; short* dst; int n8;
  switch (blockIdx.y) {
    case 0:  src = x;  dst = xb;  n8 = (M_ * D_) / 8; break;
    case 1:  src = wq; dst = wqb; n8 = (D_ * D_) / 8; break;
    case 2:  src = wk; dst = wkb; n8 = (D_ * D_) / 8; break;
    case 3:  src = wv; dst = wvb; n8 = (D_ * D_) / 8; break;
    default: src = wo; dst = wob; n8 = (D_ * D_) / 8; break;
  }
  int i = blockIdx.x * 256 + threadIdx.x;
  if (i >= n8) return;
  float4 a = ((const float4*)src)[2 * i];
  float4 b = ((const float4*)src)[2 * i + 1];
  short8 o;
  o[0] = (short)f2bf(a.x); o[1] = (short)f2bf(a.y);
  o[2] = (short)f2bf(a.z); o[3] = (short)f2bf(a.w);
  o[4] = (short)f2bf(b.x); o[5] = (short)f2bf(b.y);
  o[6] = (short)f2bf(b.z); o[7] = (short)f2bf(b.w);
  ((short8*)dst)[i] = o;
}

// ---------------------------------------------------------------- QKV projection
// m97 structure, BK=32 (R5 config — BK=64 regressed, m132 lesson).
// C[m][n] = sum_k A[m][k]*W[n][k]; writes [B,H,S,HD] bf16; Q scaled 0.125*log2e.
__global__ __launch_bounds__(256) void gemm_qkv(
    const short* __restrict__ xb,  const short* __restrict__ wqb,
    const short* __restrict__ wkb, const short* __restrict__ wvb,
    short* __restrict__ qo, short* __restrict__ ko, short* __restrict__ vo) {
  __shared__ alignas(16) short As[128 * 32];   // row-major, 64B/row
  __shared__ alignas(16) short Bs[128 * 32];
  const int tid  = threadIdx.x;
  const int lane = tid & 63, wid = tid >> 6;
  const int quad = lane >> 4, l16 = lane & 15;
  const int bn = blockIdx.x, bm = blockIdx.y, z = blockIdx.z;
  const short* wsel = (z == 0) ? wqb : ((z == 1) ? wkb : wvb);
  short*       osel = (z == 0) ? qo  : ((z == 1) ? ko  : vo);
  const float scale = (z == 0) ? 0.125f * 1.44269504f : 1.0f;
  const int lrow = wid * 32 + (lane >> 2);
  const int lcol = (lane & 3) * 8;             // shorts
  const short* ag0 = xb   + (bm * 128 + lrow) * D_ + lcol;
  const short* ag1 = ag0 + 16 * D_;
  const short* bg0 = wsel + (bn * 128 + lrow) * D_ + lcol;
  const short* bg1 = bg0 + 16 * D_;
  short* la0 = &As[(wid * 32) * 32];
  short* la1 = &As[(wid * 32 + 16) * 32];
  short* lb0 = &Bs[(wid * 32) * 32];
  short* lb1 = &Bs[(wid * 32 + 16) * 32];
  const int wm = (wid & 1) * 64, wn = (wid >> 1) * 64;
  floatx4 acc[4][4];
#pragma unroll
  for (int i = 0; i < 4; i++)
#pragma unroll
    for (int j = 0; j < 4; j++) acc[i][j] = (floatx4){0.f, 0.f, 0.f, 0.f};

  for (int k0 = 0; k0 < D_; k0 += 32) {
    __syncthreads();
    gl_lds16(ag0 + k0, la0);
    gl_lds16(ag1 + k0, la1);
    gl_lds16(bg0 + k0, lb0);
    gl_lds16(bg1 + k0, lb1);
    __syncthreads();                 // vmcnt(0) drain -> LDS ready
    short8 af[4], bf[4];
#pragma unroll
    for (int t = 0; t < 4; t++) af[t] = *(const short8*)&As[(wm + t * 16 + l16) * 32 + quad * 8];
#pragma unroll
    for (int t = 0; t < 4; t++) bf[t] = *(const short8*)&Bs[(wn + t * 16 + l16) * 32 + quad * 8];
#pragma unroll
    for (int tm = 0; tm < 4; tm++)
#pragma unroll
      for (int tn = 0; tn < 4; tn++)
        acc[tm][tn] = __builtin_amdgcn_mfma_f32_16x16x32_bf16(af[tm], bf[tn], acc[tm][tn], 0, 0, 0);
  }
#pragma unroll
  for (int tm = 0; tm < 4; tm++) {
#pragma unroll
    for (int tn = 0; tn < 4; tn++) {
      int n = bn * 128 + wn + tn * 16 + l16;
      int h = n >> 6, hd = n & 63;
#pragma unroll
      for (int r = 0; r < 4; r++) {
        int m = bm * 128 + wm + tm * 16 + quad * 4 + r;
        int b = m >> 11, s = m & 2047;
        osel[((b * H_ + h) * S_ + s) * HD_ + hd] = (short)f2bf(acc[tm][tn][r] * scale);
      }
    }
  }
}

// ---------------------------------------------------------------- V transpose
// V [BH][S][HD] -> Vt [BH][HD][S], 64x64 LDS tiles
__global__ __launch_bounds__(256) void transpose_v(
    const short* __restrict__ v, short* __restrict__ vt) {
  __shared__ alignas(16) short t[64][72];
  const int tid = threadIdx.x;
  const int s0 = blockIdx.x * 64;
  const int base = blockIdx.y * (S_ * HD_);
  const int row = tid >> 2, c8 = (tid & 3) * 16;
  short8 a0 = *(const short8*)(v + base + (s0 + row) * HD_ + c8);
  short8 a1 = *(const short8*)(v + base + (s0 + row) * HD_ + c8 + 8);
  *(short8*)&t[row][c8]     = a0;
  *(short8*)&t[row][c8 + 8] = a1;
  __syncthreads();
  short8 o0, o1;
#pragma unroll
  for (int j = 0; j < 8; j++) {
    o0[j] = t[c8 + j][row];
    o1[j] = t[c8 + 8 + j][row];
  }
  *(short8*)(vt + base + row * S_ + s0 + c8)     = o0;
  *(short8*)(vt + base + row * S_ + s0 + c8 + 8) = o1;
}

// ---------------------------------------------------------------- output projection
__global__ __launch_bounds__(256) void gemm_out(
    const short* __restrict__ cx, const short* __restrict__ wob,
    const float* __restrict__ bo, float* __restrict__ out) {
  __shared__ alignas(16) short As[128 * 32];
  __shared__ alignas(16) short Bs[128 * 32];
  const int tid  = threadIdx.x;
  const int lane = tid & 63, wid = tid >> 6;
  const int quad = lane >> 4, l16 = lane & 15;
  const int bn = blockIdx.x, bm = blockIdx.y;
  const int lrow = wid * 32 + (lane >> 2);
  const int lcol = (lane & 3) * 8;
  const short* ag0 = cx  + (bm * 128 + lrow) * D_ + lcol;
  const short* ag1 = ag0 + 16 * D_;
  const short* bg0 = wob + (bn * 128 + lrow) * D_ + lcol;
  const short* bg1 = bg0 + 16 * D_;
  short* la0 = &As[(wid * 32) * 32];
  short* la1 = &As[(wid * 32 + 16) * 32];
  short* lb0 = &Bs[(wid * 32) * 32];
  short* lb1 = &Bs[(wid * 32 + 16) * 32];
  const int wm = (wid & 1) * 64, wn = (wid >> 1) * 64;
  floatx4 acc[4][4];
#pragma unroll
  for (int i = 0; i < 4; i++)
#pragma unroll
    for (int j = 0; j < 4; j++) acc[i][j] = (floatx4){0.f, 0.f, 0.f, 0.f};

  for (int k0 = 0; k0 < D_; k0 += 32) {
    __syncthreads();
    gl_lds16(ag0 + k0, la0);
    gl_lds16(ag1 + k0, la1);
    gl_lds16(bg0 + k0, lb0);
    gl_lds16(bg1 + k0, lb1);
    __syncthreads();
    short8 af[4], bf[4];
#pragma unroll
    for (int t = 0; t < 4; t++) af[t] = *(const short8*)&As[(wm + t * 16 + l16) * 32 + quad * 8];
#pragma unroll
    for (int t = 0; t < 4; t++) bf[t] = *(const short8*)&Bs[(wn + t * 16 + l16) * 32 + quad * 8];
#pragma unroll
    for (int tm = 0; tm < 4; tm++)
#pragma unroll
      for (int tn = 0; tn < 4; tn++)
        acc[tm][tn] = __builtin_amdgcn_mfma_f32_16x16x32_bf16(af[tm], bf[tn], acc[tm][tn], 0, 0, 0);
  }
#pragma unroll
  for (int tn = 0; tn < 4; tn++) {
    int n = bn * 128 + wn + tn * 16 + l16;
    float bias = bo[n];
#pragma unroll
    for (int tm = 0; tm < 4; tm++) {
#pragma unroll
      for (int r = 0; r < 4; r++) {
        int m = bm * 128 + wm + tm * 16 + quad * 4 + r;
        out[m * D_ + n] = acc[tm][tn][r] + bias;
      }
    }
  }
}

// ---------------------------------------------------------------- flash attention
// In-block K-split x2: 512 threads = 8 waves. Group g = waves 4g..4g+3 processes
// k-tiles kt ≡ g (mod 2) for the SAME 64 Q-rows (wave w4 owns rows q0..q0+15).
// Fixed-rebase softmax (p = 2^(y-32), no running max) => partial (o, lsum) over
// disjoint K-sets add linearly; groups merge through LDS at the epilogue.
// Critical path halves: longest block 32 -> 16 serial k-tile iterations.
// grid (16..32 LPT, B*H).
__global__ __launch_bounds__(512) void attn_kernel(
    const short* __restrict__ qbuf, const short* __restrict__ kbuf,
    const short* __restrict__ vtbuf, short* __restrict__ ctx) {
  __shared__ alignas(16) short Ks[2][64][72];   // [group][s][hd]
  __shared__ alignas(16) short Vs[2][64][72];   // [group][hd][s]
  __shared__ alignas(16) short Ps[8][16][72];   // per-wave P
  __shared__ alignas(16) float Fs[4][64][20];   // group-1 partials for merge
  const int tid  = threadIdx.x;
  const int lane = tid & 63, wid8 = tid >> 6;
  const int g = tid >> 8, w4 = wid8 & 3, t8 = tid & 255;
  const int quad = lane >> 4, l16 = lane & 15;
  const int qtile = 31 - blockIdx.x, bh = blockIdx.y;   // LPT: longest first
  const int base = bh * (S_ * HD_);
  const int q0 = qtile * 64 + w4 * 16;

  short8 qf0 = *(const short8*)(qbuf + base + (q0 + l16) * HD_ + quad * 8);
  short8 qf1 = *(const short8*)(qbuf + base + (q0 + l16) * HD_ + 32 + quad * 8);

  float lsum[4];
  floatx4 o[4];
#pragma unroll
  for (int r = 0; r < 4; r++) lsum[r] = 0.f;
#pragma unroll
  for (int nt = 0; nt < 4; nt++) o[nt] = (floatx4){0.f, 0.f, 0.f, 0.f};

  const int row = t8 >> 2, c8 = (t8 & 3) * 16;   // staging coords (per group)
  const short* kg = kbuf  + base + row * HD_ + c8;
  const short* vg = vtbuf + base + row * S_  + c8;  // row = hd
  // preload group's first tile kt = g (always a valid memory region)
  short8 kv0 = *(const short8*)(kg + g * 64 * HD_);
  short8 kv1 = *(const short8*)(kg + g * 64 * HD_ + 8);
  short8 vv0 = *(const short8*)(vg + g * 64);
  short8 vv1 = *(const short8*)(vg + g * 64 + 8);

  const int ntile = qtile + 1;
  const int jmax = (ntile + 1) >> 1;          // group-0 tile count (>= group-1's)
  const int ng   = (g == 0) ? jmax : (ntile >> 1);

  for (int j = 0; j < jmax; j++) {
    const int kt = 2 * j + g;
    __syncthreads();
    *(short8*)&Ks[g][row][c8]     = kv0;
    *(short8*)&Ks[g][row][c8 + 8] = kv1;
    *(short8*)&Vs[g][row][c8]     = vv0;
    *(short8*)&Vs[g][row][c8 + 8] = vv1;
    __syncthreads();
    {   // prefetch group's next tile (clamped; reload harmless)
      int ktn = 2 * (j + 1) + g;
      if (ktn > qtile) ktn = qtile;
      const short* kgn = kg + ktn * 64 * HD_;
      const short* vgn = vg + ktn * 64;
      kv0 = *(const short8*)(kgn);
      kv1 = *(const short8*)(kgn + 8);
      vv0 = *(const short8*)(vgn);
      vv1 = *(const short8*)(vgn + 8);
    }
    if (j < ng && kt * 64 <= q0 + 15) {   // group has this tile & not fully masked
      floatx4 sc[4];
#pragma unroll
      for (int ct = 0; ct < 4; ct++) {
        short8 kb0 = *(const short8*)&Ks[g][ct * 16 + l16][quad * 8];
        short8 kb1 = *(const short8*)&Ks[g][ct * 16 + l16][32 + quad * 8];
        floatx4 zz = (floatx4){0.f, 0.f, 0.f, 0.f};
        zz     = __builtin_amdgcn_mfma_f32_16x16x32_bf16(qf0, kb0, zz, 0, 0, 0);
        sc[ct] = __builtin_amdgcn_mfma_f32_16x16x32_bf16(qf1, kb1, zz, 0, 0, 0);
      }
      if (kt * 64 + 63 > q0) {            // diagonal overlap: causal mask
#pragma unroll
        for (int ct = 0; ct < 4; ct++)
#pragma unroll
          for (int r = 0; r < 4; r++)
            if (kt * 64 + ct * 16 + l16 > q0 + quad * 4 + r) sc[ct][r] = -INFINITY;
      }
#pragma unroll
      for (int r = 0; r < 4; r++)
#pragma unroll
        for (int ct = 0; ct < 4; ct++) {
          float p = __builtin_amdgcn_exp2f(sc[ct][r] - 32.0f);
          lsum[r] += p;
          Ps[wid8][quad * 4 + r][ct * 16 + l16] = (short)(__float_as_uint(p) >> 16);
        }
#pragma unroll
      for (int ks = 0; ks < 2; ks++) {
        short8 pa = *(const short8*)&Ps[wid8][l16][ks * 32 + quad * 8];
#pragma unroll
        for (int nt = 0; nt < 4; nt++) {
          short8 vb = *(const short8*)&Vs[g][nt * 16 + l16][ks * 32 + quad * 8];
          o[nt] = __builtin_amdgcn_mfma_f32_16x16x32_bf16(pa, vb, o[nt], 0, 0, 0);
        }
      }
    }
  }
  // ---- merge groups: partials add linearly (shared 2^-32 rebase) ----
  __syncthreads();
  if (g == 1) {
#pragma unroll
    for (int nt = 0; nt < 4; nt++)
#pragma unroll
      for (int r = 0; r < 4; r++) Fs[w4][lane][nt * 4 + r] = o[nt][r];
#pragma unroll
    for (int r = 0; r < 4; r++) Fs[w4][lane][16 + r] = lsum[r];
  }
  __syncthreads();
  if (g == 0) {
#pragma unroll
    for (int nt = 0; nt < 4; nt++)
#pragma unroll
      for (int r = 0; r < 4; r++) o[nt][r] += Fs[w4][lane][nt * 4 + r];
#pragma unroll
    for (int r = 0; r < 4; r++) {
      float ls = lsum[r] + Fs[w4][lane][16 + r];
      ls += __shfl_xor(ls, 1);
      ls += __shfl_xor(ls, 2);
      ls += __shfl_xor(ls, 4);
      ls += __shfl_xor(ls, 8);
      float linv = 1.f / ls;
      int s = q0 + quad * 4 + r;
      int rowbase = ((bh >> 4) * S_ + s) * D_ + (bh & 15) * HD_;
#pragma unroll
      for (int nt = 0; nt < 4; nt++)
        ctx[rowbase + nt * 16 + l16] = (short)f2bf(o[nt][r] * linv);
    }
  }
}

// ---------------------------------------------------------------- launch
extern "C" void kernel_launch(void* const* d_in, const int* in_sizes, int n_in,
                              void* d_out, int out_size, void* d_ws, size_t ws_size,
                              hipStream_t stream) {
  const float* x  = (const float*)d_in[0];
  const float* wq = (const float*)d_in[1];
  const float* wk = (const float*)d_in[2];
  const float* wv = (const float*)d_in[3];
  const float* wo = (const float*)d_in[4];
  const float* bo = (const float*)d_in[5];
  float* out = (float*)d_out;

  char* ws = (char*)d_ws;
  short* xb  = (short*)(ws);                    // 8 MB
  short* wqb = (short*)(ws + (8u  << 20));      // 2 MB
  short* wkb = (short*)(ws + (10u << 20));      // 2 MB
  short* wvb = (short*)(ws + (12u << 20));      // 2 MB
  short* wob = (short*)(ws + (14u << 20));      // 2 MB
  short* qb  = (short*)(ws + (16u << 20));      // 8 MB  [B,H,S,HD]
  short* kb  = (short*)(ws + (24u << 20));      // 8 MB
  short* vb  = (short*)(ws + (32u << 20));      // 8 MB
  short* cx  = (short*)(ws + (40u << 20));      // 8 MB  [M,D]
  short* vtb = (short*)(ws + (48u << 20));      // 8 MB  [B,H,HD,S] -> total 56 MB

  cast_kernel<<<dim3(2048, 5), 256, 0, stream>>>(x, wq, wk, wv, wo, xb, wqb, wkb, wvb, wob);
  gemm_qkv   <<<dim3(8, 32, 3), 256, 0, stream>>>(xb, wqb, wkb, wvb, qb, kb, vb);
  transpose_v<<<dim3(32, 32),   256, 0, stream>>>(vb, vtb);
  attn_kernel<<<dim3(32, 32),   512, 0, stream>>>(qb, kb, vtb, cx);
  gemm_out   <<<dim3(8, 32),    256, 0, stream>>>(cx, wob, bo, out);
}

// Round 8
// 189.017 us; speedup vs baseline: 1.2109x; 1.1043x over previous
//
#include <hip/hip_runtime.h>

#define B_  2
#define S_  2048
#define D_  1024
#define H_  16
#define HD_ 64
#define M_  4096   // B_*S_

typedef __attribute__((ext_vector_type(8))) short  short8;
typedef __attribute__((ext_vector_type(4))) float  floatx4;

__device__ __forceinline__ unsigned short f2bf(float f) {
  unsigned int u = __float_as_uint(f);
  u = (u + 0x7fffu + ((u >> 16) & 1u)) >> 16;   // RNE
  return (unsigned short)u;
}

// async global->LDS, 16B per lane; lds dest = wave-uniform base + lane*16
__device__ __forceinline__ void gl_lds16(const short* g, short* l) {
  __builtin_amdgcn_global_load_lds(
      (const __attribute__((address_space(1))) unsigned int*)g,
      (__attribute__((address_space(3))) unsigned int*)l, 16, 0, 0);
}

// ---------------------------------------------------------------- cast fp32->bf16
__global__ __launch_bounds__(256) void cast_kernel(
    const float* __restrict__ x,  const float* __restrict__ wq,
    const float* __restrict__ wk, const float* __restrict__ wv,
    const float* __restrict__ wo,
    short* __restrict__ xb,  short* __restrict__ wqb, short* __restrict__ wkb,
    short* __restrict__ wvb, short* __restrict__ wob) {
  const float* src; short* dst; int n8;
  switch (blockIdx.y) {
    case 0:  src = x;  dst = xb;  n8 = (M_ * D_) / 8; break;
    case 1:  src = wq; dst = wqb; n8 = (D_ * D_) / 8; break;
    case 2:  src = wk; dst = wkb; n8 = (D_ * D_) / 8; break;
    case 3:  src = wv; dst = wvb; n8 = (D_ * D_) / 8; break;
    default: src = wo; dst = wob; n8 = (D_ * D_) / 8; break;
  }
  int i = blockIdx.x * 256 + threadIdx.x;
  if (i >= n8) return;
  float4 a = ((const float4*)src)[2 * i];
  float4 b = ((const float4*)src)[2 * i + 1];
  short8 o;
  o[0] = (short)f2bf(a.x); o[1] = (short)f2bf(a.y);
  o[2] = (short)f2bf(a.z); o[3] = (short)f2bf(a.w);
  o[4] = (short)f2bf(b.x); o[5] = (short)f2bf(b.y);
  o[6] = (short)f2bf(b.z); o[7] = (short)f2bf(b.w);
  ((short8*)dst)[i] = o;
}

// ---------------------------------------------------------------- QKV projection
// m97 structure, BK=32. C[m][n] = sum_k A[m][k]*W[n][k].
// z=0: Q (scaled 0.125*log2e) -> [B,H,S,HD]; z=1: K -> [B,H,S,HD];
// z=2: V written TRANSPOSED -> Vt [B,H,HD,S] (transpose kernel fused away;
//      scattered 2B stores merge to full lines in L2 — same store count).
__global__ __launch_bounds__(256) void gemm_qkv(
    const short* __restrict__ xb,  const short* __restrict__ wqb,
    const short* __restrict__ wkb, const short* __restrict__ wvb,
    short* __restrict__ qo, short* __restrict__ ko, short* __restrict__ vto) {
  __shared__ alignas(16) short As[128 * 32];   // row-major, 64B/row
  __shared__ alignas(16) short Bs[128 * 32];
  const int tid  = threadIdx.x;
  const int lane = tid & 63, wid = tid >> 6;
  const int quad = lane >> 4, l16 = lane & 15;
  const int bn = blockIdx.x, bm = blockIdx.y, z = blockIdx.z;
  const short* wsel = (z == 0) ? wqb : ((z == 1) ? wkb : wvb);
  const float scale = (z == 0) ? 0.125f * 1.44269504f : 1.0f;
  const int lrow = wid * 32 + (lane >> 2);
  const int lcol = (lane & 3) * 8;             // shorts
  const short* ag0 = xb   + (bm * 128 + lrow) * D_ + lcol;
  const short* ag1 = ag0 + 16 * D_;
  const short* bg0 = wsel + (bn * 128 + lrow) * D_ + lcol;
  const short* bg1 = bg0 + 16 * D_;
  short* la0 = &As[(wid * 32) * 32];
  short* la1 = &As[(wid * 32 + 16) * 32];
  short* lb0 = &Bs[(wid * 32) * 32];
  short* lb1 = &Bs[(wid * 32 + 16) * 32];
  const int wm = (wid & 1) * 64, wn = (wid >> 1) * 64;
  floatx4 acc[4][4];
#pragma unroll
  for (int i = 0; i < 4; i++)
#pragma unroll
    for (int j = 0; j < 4; j++) acc[i][j] = (floatx4){0.f, 0.f, 0.f, 0.f};

  for (int k0 = 0; k0 < D_; k0 += 32) {
    __syncthreads();
    gl_lds16(ag0 + k0, la0);
    gl_lds16(ag1 + k0, la1);
    gl_lds16(bg0 + k0, lb0);
    gl_lds16(bg1 + k0, lb1);
    __syncthreads();                 // vmcnt(0) drain -> LDS ready
    short8 af[4], bf[4];
#pragma unroll
    for (int t = 0; t < 4; t++) af[t] = *(const short8*)&As[(wm + t * 16 + l16) * 32 + quad * 8];
#pragma unroll
    for (int t = 0; t < 4; t++) bf[t] = *(const short8*)&Bs[(wn + t * 16 + l16) * 32 + quad * 8];
#pragma unroll
    for (int tm = 0; tm < 4; tm++)
#pragma unroll
      for (int tn = 0; tn < 4; tn++)
        acc[tm][tn] = __builtin_amdgcn_mfma_f32_16x16x32_bf16(af[tm], bf[tn], acc[tm][tn], 0, 0, 0);
  }
#pragma unroll
  for (int tm = 0; tm < 4; tm++) {
#pragma unroll
    for (int tn = 0; tn < 4; tn++) {
      int n = bn * 128 + wn + tn * 16 + l16;
      int h = n >> 6, hd = n & 63;
#pragma unroll
      for (int r = 0; r < 4; r++) {
        int m = bm * 128 + wm + tm * 16 + quad * 4 + r;
        int b = m >> 11, s = m & 2047;
        unsigned short val = f2bf(acc[tm][tn][r] * scale);
        if (z == 2)       // Vt [B,H,HD,S]
          vto[((b * H_ + h) * HD_ + hd) * S_ + s] = (short)val;
        else if (z == 1)
          ko[((b * H_ + h) * S_ + s) * HD_ + hd] = (short)val;
        else
          qo[((b * H_ + h) * S_ + s) * HD_ + hd] = (short)val;
      }
    }
  }
}

// ---------------------------------------------------------------- output projection
__global__ __launch_bounds__(256) void gemm_out(
    const short* __restrict__ cx, const short* __restrict__ wob,
    const float* __restrict__ bo, float* __restrict__ out) {
  __shared__ alignas(16) short As[128 * 32];
  __shared__ alignas(16) short Bs[128 * 32];
  const int tid  = threadIdx.x;
  const int lane = tid & 63, wid = tid >> 6;
  const int quad = lane >> 4, l16 = lane & 15;
  const int bn = blockIdx.x, bm = blockIdx.y;
  const int lrow = wid * 32 + (lane >> 2);
  const int lcol = (lane & 3) * 8;
  const short* ag0 = cx  + (bm * 128 + lrow) * D_ + lcol;
  const short* ag1 = ag0 + 16 * D_;
  const short* bg0 = wob + (bn * 128 + lrow) * D_ + lcol;
  const short* bg1 = bg0 + 16 * D_;
  short* la0 = &As[(wid * 32) * 32];
  short* la1 = &As[(wid * 32 + 16) * 32];
  short* lb0 = &Bs[(wid * 32) * 32];
  short* lb1 = &Bs[(wid * 32 + 16) * 32];
  const int wm = (wid & 1) * 64, wn = (wid >> 1) * 64;
  floatx4 acc[4][4];
#pragma unroll
  for (int i = 0; i < 4; i++)
#pragma unroll
    for (int j = 0; j < 4; j++) acc[i][j] = (floatx4){0.f, 0.f, 0.f, 0.f};

  for (int k0 = 0; k0 < D_; k0 += 32) {
    __syncthreads();
    gl_lds16(ag0 + k0, la0);
    gl_lds16(ag1 + k0, la1);
    gl_lds16(bg0 + k0, lb0);
    gl_lds16(bg1 + k0, lb1);
    __syncthreads();
    short8 af[4], bf[4];
#pragma unroll
    for (int t = 0; t < 4; t++) af[t] = *(const short8*)&As[(wm + t * 16 + l16) * 32 + quad * 8];
#pragma unroll
    for (int t = 0; t < 4; t++) bf[t] = *(const short8*)&Bs[(wn + t * 16 + l16) * 32 + quad * 8];
#pragma unroll
    for (int tm = 0; tm < 4; tm++)
#pragma unroll
      for (int tn = 0; tn < 4; tn++)
        acc[tm][tn] = __builtin_amdgcn_mfma_f32_16x16x32_bf16(af[tm], bf[tn], acc[tm][tn], 0, 0, 0);
  }
#pragma unroll
  for (int tn = 0; tn < 4; tn++) {
    int n = bn * 128 + wn + tn * 16 + l16;
    float bias = bo[n];
#pragma unroll
    for (int tm = 0; tm < 4; tm++) {
#pragma unroll
      for (int r = 0; r < 4; r++) {
        int m = bm * 128 + wm + tm * 16 + quad * 4 + r;
        out[m * D_ + n] = acc[tm][tn][r] + bias;
      }
    }
  }
}

// ---------------------------------------------------------------- flash attention
// R3 structure (single-buffer K/V, 2 barriers/iter, reg prefetch) + EXACT
// per-CU load balancing. With blockID->CU ~ id%256 round-robin and grid
// (32,32), a CU's 4 blocks share bx and have by = b0+{0,8,16,24}. Mapping
//   qblk = ((by>>3)&1) ? bx : 31-bx
// gives per-CU depth (32-bx)+(bx+1)+(32-bx)+(bx+1) = 66 slots for EVERY CU
// (vs 128 worst-case before). All 4 blocks LDS-resident (27.6 KB).
// Fixed-rebase softmax p = 2^(y-32), y = score*log2e folded into Q scale.
__global__ __launch_bounds__(256) void attn_kernel(
    const short* __restrict__ qbuf, const short* __restrict__ kbuf,
    const short* __restrict__ vtbuf, short* __restrict__ ctx) {
  __shared__ alignas(16) short Ks[64][72];      // [s][hd]
  __shared__ alignas(16) short Vs[64][72];      // [hd][s]
  __shared__ alignas(16) short Ps[4][16][72];   // per-wave P (wave-local)
  const int tid  = threadIdx.x;
  const int lane = tid & 63, wid = tid >> 6;
  const int quad = lane >> 4, l16 = lane & 15;
  const int bx = blockIdx.x, by = blockIdx.y;
  const int qblk = ((by >> 3) & 1) ? bx : (31 - bx);   // balanced depth per CU
  const int bh = by;
  const int base = bh * (S_ * HD_);
  const int q0 = qblk * 64 + wid * 16;

  short8 qf0 = *(const short8*)(qbuf + base + (q0 + l16) * HD_ + quad * 8);
  short8 qf1 = *(const short8*)(qbuf + base + (q0 + l16) * HD_ + 32 + quad * 8);

  float lsum[4];
  floatx4 o[4];
#pragma unroll
  for (int r = 0; r < 4; r++) lsum[r] = 0.f;
#pragma unroll
  for (int nt = 0; nt < 4; nt++) o[nt] = (floatx4){0.f, 0.f, 0.f, 0.f};

  const int row = tid >> 2, c8 = (tid & 3) * 16;   // staging coords
  const short* kg = kbuf  + base + row * HD_ + c8;
  const short* vg = vtbuf + base + row * S_  + c8;  // row = hd
  short8 kv0 = *(const short8*)(kg);
  short8 kv1 = *(const short8*)(kg + 8);
  short8 vv0 = *(const short8*)(vg);
  short8 vv1 = *(const short8*)(vg + 8);

  for (int kt = 0; kt <= qblk; kt++) {
    __syncthreads();
    *(short8*)&Ks[row][c8]     = kv0;
    *(short8*)&Ks[row][c8 + 8] = kv1;
    *(short8*)&Vs[row][c8]     = vv0;
    *(short8*)&Vs[row][c8 + 8] = vv1;
    __syncthreads();
    {   // prefetch next tile (clamped; last-iter value unused)
      const int ktn = (kt < qblk) ? kt + 1 : kt;
      const short* kgn = kg + ktn * 64 * HD_;
      const short* vgn = vg + ktn * 64;
      kv0 = *(const short8*)(kgn);
      kv1 = *(const short8*)(kgn + 8);
      vv0 = *(const short8*)(vgn);
      vv1 = *(const short8*)(vgn + 8);
    }

    floatx4 sc[4];
#pragma unroll
    for (int ct = 0; ct < 4; ct++) {
      short8 kb0 = *(const short8*)&Ks[ct * 16 + l16][quad * 8];
      short8 kb1 = *(const short8*)&Ks[ct * 16 + l16][32 + quad * 8];
      floatx4 zz = (floatx4){0.f, 0.f, 0.f, 0.f};
      zz     = __builtin_amdgcn_mfma_f32_16x16x32_bf16(qf0, kb0, zz, 0, 0, 0);
      sc[ct] = __builtin_amdgcn_mfma_f32_16x16x32_bf16(qf1, kb1, zz, 0, 0, 0);
    }
    if (kt == qblk) {            // diagonal tile: causal mask (2^-inf = 0)
#pragma unroll
      for (int ct = 0; ct < 4; ct++)
#pragma unroll
        for (int r = 0; r < 4; r++)
          if (ct * 16 + l16 > wid * 16 + quad * 4 + r) sc[ct][r] = -INFINITY;
    }
#pragma unroll
    for (int r = 0; r < 4; r++) {
#pragma unroll
      for (int ct = 0; ct < 4; ct++) {
        float p = __builtin_amdgcn_exp2f(sc[ct][r] - 32.0f);
        lsum[r] += p;
        // truncating bf16 (p >= 0): 1 op vs 3 for RNE
        Ps[wid][quad * 4 + r][ct * 16 + l16] = (short)(__float_as_uint(p) >> 16);
      }
    }
    // PV: o += P[16x64] * V[64x64]   (Ps wave-local; lgkmcnt orders it)
#pragma unroll
    for (int ks = 0; ks < 2; ks++) {
      short8 pa = *(const short8*)&Ps[wid][l16][ks * 32 + quad * 8];
#pragma unroll
      for (int nt = 0; nt < 4; nt++) {
        short8 vb = *(const short8*)&Vs[nt * 16 + l16][ks * 32 + quad * 8];
        o[nt] = __builtin_amdgcn_mfma_f32_16x16x32_bf16(pa, vb, o[nt], 0, 0, 0);
      }
    }
  }
  // epilogue: one cross-lane l reduction, then ctx[b*2048+s][h*64+col] = o/l
#pragma unroll
  for (int r = 0; r < 4; r++) {
    float ls = lsum[r];
    ls += __shfl_xor(ls, 1);
    ls += __shfl_xor(ls, 2);
    ls += __shfl_xor(ls, 4);
    ls += __shfl_xor(ls, 8);
    float linv = 1.f / ls;
    int s = q0 + quad * 4 + r;
    int rowbase = ((bh >> 4) * S_ + s) * D_ + (bh & 15) * HD_;
#pragma unroll
    for (int nt = 0; nt < 4; nt++)
      ctx[rowbase + nt * 16 + l16] = (short)f2bf(o[nt][r] * linv);
  }
}

// ---------------------------------------------------------------- launch
extern "C" void kernel_launch(void* const* d_in, const int* in_sizes, int n_in,
                              void* d_out, int out_size, void* d_ws, size_t ws_size,
                              hipStream_t stream) {
  const float* x  = (const float*)d_in[0];
  const float* wq = (const float*)d_in[1];
  const float* wk = (const float*)d_in[2];
  const float* wv = (const float*)d_in[3];
  const float* wo = (const float*)d_in[4];
  const float* bo = (const float*)d_in[5];
  float* out = (float*)d_out;

  char* ws = (char*)d_ws;
  short* xb  = (short*)(ws);                    // 8 MB
  short* wqb = (short*)(ws + (8u  << 20));      // 2 MB
  short* wkb = (short*)(ws + (10u << 20));      // 2 MB
  short* wvb = (short*)(ws + (12u << 20));      // 2 MB
  short* wob = (short*)(ws + (14u << 20));      // 2 MB
  short* qb  = (short*)(ws + (16u << 20));      // 8 MB  [B,H,S,HD]
  short* kb  = (short*)(ws + (24u << 20));      // 8 MB  [B,H,S,HD]
  short* cx  = (short*)(ws + (32u << 20));      // 8 MB  [M,D]
  short* vtb = (short*)(ws + (40u << 20));      // 8 MB  [B,H,HD,S] -> total 48 MB

  cast_kernel<<<dim3(2048, 5), 256, 0, stream>>>(x, wq, wk, wv, wo, xb, wqb, wkb, wvb, wob);
  gemm_qkv   <<<dim3(8, 32, 3), 256, 0, stream>>>(xb, wqb, wkb, wvb, qb, kb, vtb);
  attn_kernel<<<dim3(32, 32),   256, 0, stream>>>(qb, kb, vtb, cx);
  gemm_out   <<<dim3(8, 32),    256, 0, stream>>>(cx, wob, bo, out);
}